// Round 6
// baseline (310.691 us; speedup 1.0000x reference)
//
#include <hip/hip_runtime.h>

// CRF forward (log-partition minus gold score), B=2048, L=512, T=32.
// ONE batch per wave64 (2048 blocks). Scaled linear-space forward:
//   a[j] <- (sum_i a[i]*E[i][j]) * exp(emit[t][j]),  E = exp(trans)
// Cross-lane matvec entirely in VALU: K-split over 4 rows of 16 lanes with
// DPP row_newbcast broadcasts + gfx950 permlane16/32_swap combines in a
// Q/R layout ping-pong (no LDS on the recurrence chain).
// R5 lesson: without launch_bounds the allocator capped VGPRs at 36 and
// spilled EcQ/EcR + pipeline to scratch (WRITE_SIZE 82 MB, 157 us).
// __launch_bounds__(64,2) -> 256-VGPR cap, no spills; occupancy is
// grid-bound (8 waves/CU) regardless.

constexpr int TT = 32;
constexpr int LL = 512;

#define L2E  1.4426950408889634f
#define LN2f 0.6931471805599453f

// DPP row_newbcast:b — broadcast lane b within each row of 16 (gfx90a+)
#define DPPBC(b, vv) __int_as_float(__builtin_amdgcn_update_dpp( \
    0, __float_as_int(vv), 0x150 + (b), 0xF, 0xF, false))

__device__ __forceinline__ float swap16(float v, int lane) {
#if __has_builtin(__builtin_amdgcn_permlane16_swap)
  auto p = __builtin_amdgcn_permlane16_swap(__float_as_uint(v), __float_as_uint(v),
                                            false, false);
  // p[0]=[r0,r0,r2,r2], p[1]=[r1,r1,r3,r3]; even rows need p[1], odd p[0]
  return __uint_as_float((lane & 16) ? p[0] : p[1]);
#else
  // ds_swizzle xor-16 within 32-lane groups == lane^16 globally
  return __int_as_float(__builtin_amdgcn_ds_swizzle(__float_as_int(v), 0x401F));
#endif
}

__device__ __forceinline__ float swap32(float v, int lane) {
#if __has_builtin(__builtin_amdgcn_permlane32_swap)
  auto p = __builtin_amdgcn_permlane32_swap(__float_as_uint(v), __float_as_uint(v),
                                            false, false);
  // p[0]=[r0,r1,r0,r1], p[1]=[r2,r3,r2,r3]; lower half needs p[1], upper p[0]
  return __uint_as_float((lane & 32) ? p[0] : p[1]);
#else
  return __int_as_float(__builtin_amdgcn_ds_bpermute((lane ^ 32) << 2,
                                                     __float_as_int(v)));
#endif
}

// 16 partial FMAs: row r accumulates its 16-term i-half for its column
#define DO_FMAS(EC) \
  acc0 = DPPBC(0, av)  * EC[0];            \
  acc1 = DPPBC(1, av)  * EC[1];            \
  acc2 = DPPBC(2, av)  * EC[2];            \
  acc3 = DPPBC(3, av)  * EC[3];            \
  acc0 = fmaf(DPPBC(4, av),  EC[4],  acc0); \
  acc1 = fmaf(DPPBC(5, av),  EC[5],  acc1); \
  acc2 = fmaf(DPPBC(6, av),  EC[6],  acc2); \
  acc3 = fmaf(DPPBC(7, av),  EC[7],  acc3); \
  acc0 = fmaf(DPPBC(8, av),  EC[8],  acc0); \
  acc1 = fmaf(DPPBC(9, av),  EC[9],  acc1); \
  acc2 = fmaf(DPPBC(10, av), EC[10], acc2); \
  acc3 = fmaf(DPPBC(11, av), EC[11], acc3); \
  acc0 = fmaf(DPPBC(12, av), EC[12], acc0); \
  acc1 = fmaf(DPPBC(13, av), EC[13], acc1); \
  acc2 = fmaf(DPPBC(14, av), EC[14], acc2); \
  acc3 = fmaf(DPPBC(15, av), EC[15], acc3);

// One recurrence step. PH: 0 = Q-phase (combine lane^16), 1 = R-phase (^32).
#define STEP(k, PH) do {                                            \
    const int t = tb + (k);                                         \
    float acc0, acc1, acc2, acc3;                                   \
    if (PH == 0) { DO_FMAS(EcQ) } else { DO_FMAS(EcR) }             \
    float accs = (acc0 + acc1) + (acc2 + acc3);                     \
    float oth  = (PH == 0) ? swap16(accs, lane) : swap32(accs, lane);\
    float sum  = accs + oth;                                        \
    float anew = sum * e2v[k];                                      \
    const bool valid = t < len;                                     \
    av = valid ? anew : av;                                         \
    int tagk = tg[k];                                               \
    const int jc = (PH == 0) ? jcolQ : jcolR;                       \
    float tr = s_trans[(ptag << 5) + jc];                           \
    const bool gm = (PH == 0) ? ((lane & 16) == 0) : (lane < 32);   \
    gacc += (valid && gm && (jc == tagk)) ? (eb[k] + tr) : 0.f;     \
    ptag = tagk;                                                    \
  } while (0)

__global__ __launch_bounds__(64, 2) void crf_fwd(
    const float* __restrict__ emit, const float* __restrict__ trans,
    const int* __restrict__ tags, const int* __restrict__ lengths,
    float* __restrict__ out, int B)
{
  __shared__ float s_trans[TT * TT];
  {
    const float4* t4 = (const float4*)trans;
    float4* st = (float4*)s_trans;
#pragma unroll
    for (int k = 0; k < 4; ++k)
      st[threadIdx.x + 64 * k] = t4[threadIdx.x + 64 * k];
  }
  __syncthreads();

  const int lane = threadIdx.x & 63;
  const int j16  = lane & 15;
  const int bit4 = (lane >> 4) & 1;
  const int bit5 = (lane >> 5) & 1;
  const int b = blockIdx.x;
  if (b >= B) return;

  // Q-layout: av[lane] = a[16*bit4 + j16]; its step outputs columns jcolQ.
  // R-layout: av[lane] = a[16*bit5 + j16]; outputs jcolR. jcolQ==iR, jcolR==iQ.
  const int iQ    = 16 * bit4 + j16;
  const int jcolQ = 16 * bit5 + j16;
  const int jcolR = 16 * bit4 + j16;

  // E fragments: EcQ[b] = exp(trans[16*bit4+b][jcolQ]); EcR[b] = exp(trans[16*bit5+b][jcolR])
  float EcQ[16], EcR[16];
#pragma unroll
  for (int i = 0; i < 16; ++i) {
    EcQ[i] = __builtin_amdgcn_exp2f(s_trans[(16 * bit4 + i) * TT + jcolQ] * L2E);
    EcR[i] = __builtin_amdgcn_exp2f(s_trans[(16 * bit5 + i) * TT + jcolR] * L2E);
  }

  const int len = lengths[b];
  const float* erow = emit + (size_t)b * (LL * TT);
  const int*  trow  = tags + (size_t)b * LL;

  // t = 0 prologue (layout Q)
  float e0   = erow[iQ];
  int   ptag = trow[0];
  float av   = __builtin_amdgcn_exp2f(e0 * L2E);
  float gacc = ((lane < 32) && (iQ == ptag)) ? e0 : 0.f;
  float LS   = 0.f;

  const int nch = (len - 1 + 3) >> 2;   // 4-step chunks (phases Q,R,Q,R)

  // 4-deep software pipeline (prefetch 3 chunks = 12 steps ahead)
  float eb[4], en[4], ep[4];
  int   tg[4], tgn[4], tgp[4];
#pragma unroll
  for (int k = 0; k < 4; ++k) {
    int t = 1 + k;  int tc = t < LL ? t : LL - 1;
    eb[k] = erow[tc * TT + ((k & 1) ? jcolR : jcolQ)];
    tg[k] = trow[tc];
  }
#pragma unroll
  for (int k = 0; k < 4; ++k) {
    int t = 5 + k;  int tc = t < LL ? t : LL - 1;
    en[k] = erow[tc * TT + ((k & 1) ? jcolR : jcolQ)];
    tgn[k] = trow[tc];
  }
#pragma unroll
  for (int k = 0; k < 4; ++k) {
    int t = 9 + k;  int tc = t < LL ? t : LL - 1;
    ep[k] = erow[tc * TT + ((k & 1) ? jcolR : jcolQ)];
    tgp[k] = trow[tc];
  }

  for (int c = 0; c < nch; ++c) {
    const int tb = 1 + (c << 2);

    // prefetch chunk c+3
    float eq[4]; int tgq[4];
#pragma unroll
    for (int k = 0; k < 4; ++k) {
      int t = tb + 12 + k;  int tc = t < LL ? t : LL - 1;
      eq[k]  = erow[tc * TT + ((k & 1) ? jcolR : jcolQ)];
      tgq[k] = trow[tc];
    }

    // exp(emit) for the current chunk up front (off critical path)
    float e2v[4];
#pragma unroll
    for (int k = 0; k < 4; ++k) e2v[k] = __builtin_amdgcn_exp2f(eb[k] * L2E);

    STEP(0, 0);
    STEP(1, 1);
    STEP(2, 0);
    STEP(3, 1);

    // renorm by a[0] (lane 0 holds a[0] in both layouts); logz-invariant
    float m = __builtin_amdgcn_readfirstlane(av);
    m = fmaxf(m, 1e-30f);
    float r = __builtin_amdgcn_rcpf(m);
    av *= r;
    LS += __builtin_amdgcn_logf(m);   // v_log_f32 = log2

    // rotate pipeline
#pragma unroll
    for (int k = 0; k < 4; ++k) {
      eb[k] = en[k];  tg[k] = tgn[k];
      en[k] = ep[k];  tgn[k] = tgp[k];
      ep[k] = eq[k];  tgp[k] = tgq[k];
    }
  }

  // reductions over 64 lanes: alphas appear exactly twice -> S = 2*sum(a)
  float s  = av;
  float gs = gacc;
#pragma unroll
  for (int m = 1; m <= 32; m <<= 1) {
    s  += __shfl_xor(s, m);
    gs += __shfl_xor(gs, m);
  }
  float logz = (__builtin_amdgcn_logf(s) - 1.0f + LS) * LN2f;
  if (lane == 0) out[b] = logz - gs;
}

extern "C" void kernel_launch(void* const* d_in, const int* in_sizes, int n_in,
                              void* d_out, int out_size, void* d_ws, size_t ws_size,
                              hipStream_t stream) {
  const float* emit    = (const float*)d_in[0];
  const float* trans   = (const float*)d_in[1];
  const int*   tags    = (const int*)d_in[2];
  const int*   lengths = (const int*)d_in[3];
  float*       out     = (float*)d_out;
  const int B = in_sizes[3];             // lengths is (B,)
  hipLaunchKernelGGL(crf_fwd, dim3(B), dim3(64), 0, stream,
                     emit, trans, tags, lengths, out, B);
}

// Round 7
// 284.464 us; speedup vs baseline: 1.0922x; 1.0922x over previous
//
#include <hip/hip_runtime.h>

// CRF forward (log-partition minus gold score), B=2048, L=512, T=32.
// ONE batch per wave64 (2048 blocks). Scaled linear-space forward:
//   a[j] <- (sum_i a[i]*E[i][j]) * exp(emit[t][j]),  E = exp(trans)
// Cross-lane matvec in VALU (DPP row_newbcast FMAs + permlane16/32_swap
// Q/R ping-pong). R6 lesson: buffer-rotation register copies forced a
// vmcnt wait inside the issuing chunk, collapsing the prefetch pipeline.
// R7: mod-4 circular buffers, statically indexed, zero copies -> loads
// stay in flight ~3 chunk-times; compiler emits partial vmcnt waits.

constexpr int TT = 32;
constexpr int LL = 512;

#define L2E  1.4426950408889634f
#define LN2f 0.6931471805599453f

// DPP row_newbcast:b — broadcast lane b within each row of 16 (gfx90a+)
#define DPPBC(b, vv) __int_as_float(__builtin_amdgcn_update_dpp( \
    0, __float_as_int(vv), 0x150 + (b), 0xF, 0xF, false))

__device__ __forceinline__ float swap16(float v, int lane) {
#if __has_builtin(__builtin_amdgcn_permlane16_swap)
  auto p = __builtin_amdgcn_permlane16_swap(__float_as_uint(v), __float_as_uint(v),
                                            false, false);
  // p[0]=[r0,r0,r2,r2], p[1]=[r1,r1,r3,r3]; even rows take p[1], odd p[0]
  return __uint_as_float((lane & 16) ? p[0] : p[1]);
#else
  return __int_as_float(__builtin_amdgcn_ds_swizzle(__float_as_int(v), 0x401F));
#endif
}

__device__ __forceinline__ float swap32(float v, int lane) {
#if __has_builtin(__builtin_amdgcn_permlane32_swap)
  auto p = __builtin_amdgcn_permlane32_swap(__float_as_uint(v), __float_as_uint(v),
                                            false, false);
  // p[0]=[r0,r1,r0,r1], p[1]=[r2,r3,r2,r3]; lower half takes p[1], upper p[0]
  return __uint_as_float((lane & 32) ? p[0] : p[1]);
#else
  return __int_as_float(__builtin_amdgcn_ds_bpermute((lane ^ 32) << 2,
                                                     __float_as_int(v)));
#endif
}

// 16 partial FMAs: this lane's 16-term i-half for its column
#define DO_FMAS(EC) \
  acc0 = DPPBC(0, av)  * EC[0];            \
  acc1 = DPPBC(1, av)  * EC[1];            \
  acc2 = DPPBC(2, av)  * EC[2];            \
  acc3 = DPPBC(3, av)  * EC[3];            \
  acc0 = fmaf(DPPBC(4, av),  EC[4],  acc0); \
  acc1 = fmaf(DPPBC(5, av),  EC[5],  acc1); \
  acc2 = fmaf(DPPBC(6, av),  EC[6],  acc2); \
  acc3 = fmaf(DPPBC(7, av),  EC[7],  acc3); \
  acc0 = fmaf(DPPBC(8, av),  EC[8],  acc0); \
  acc1 = fmaf(DPPBC(9, av),  EC[9],  acc1); \
  acc2 = fmaf(DPPBC(10, av), EC[10], acc2); \
  acc3 = fmaf(DPPBC(11, av), EC[11], acc3); \
  acc0 = fmaf(DPPBC(12, av), EC[12], acc0); \
  acc1 = fmaf(DPPBC(13, av), EC[13], acc1); \
  acc2 = fmaf(DPPBC(14, av), EC[14], acc2); \
  acc3 = fmaf(DPPBC(15, av), EC[15], acc3);

// One recurrence step. PH: 0 = Q-phase (combine lane^16), 1 = R-phase (^32).
#define STEP(BI, k, PH) do {                                        \
    const int t = tb + (k);                                         \
    float acc0, acc1, acc2, acc3;                                   \
    if (PH == 0) { DO_FMAS(EcQ) } else { DO_FMAS(EcR) }             \
    float accs = (acc0 + acc1) + (acc2 + acc3);                     \
    float oth  = (PH == 0) ? swap16(accs, lane) : swap32(accs, lane);\
    float sum  = accs + oth;                                        \
    float anew = sum * e2v[k];                                      \
    const bool valid = t < len;                                     \
    av = valid ? anew : av;                                         \
    int tagk = tbuf[BI][k];                                         \
    const int jc = (PH == 0) ? jcolQ : jcolR;                       \
    float tr = s_trans[(ptag << 5) + jc];                           \
    const bool gm = (PH == 0) ? ((lane & 16) == 0) : (lane < 32);   \
    gacc += (valid && gm && (jc == tagk)) ? (ebuf[BI][k] + tr) : 0.f;\
    ptag = tagk;                                                    \
  } while (0)

// Issue the 8 loads for chunk CIDX into buffer BI (no waits here)
#define LOADG(BI, CIDX) do {                                        \
    const int t0_ = 1 + ((CIDX) << 2);                              \
    _Pragma("unroll")                                               \
    for (int k = 0; k < 4; ++k) {                                   \
      int tc = min(t0_ + k, LL - 1);                                \
      ebuf[BI][k] = erow[tc * TT + ((k & 1) ? jcolR : jcolQ)];      \
      tbuf[BI][k] = trow[tc];                                       \
    }                                                               \
  } while (0)

// Process chunk CIDX from buffer BI (4 steps + renorm)
#define PROC(BI, CIDX) do {                                         \
    const int tb = 1 + ((CIDX) << 2);                               \
    float e2v[4];                                                   \
    _Pragma("unroll")                                               \
    for (int k = 0; k < 4; ++k)                                     \
      e2v[k] = __builtin_amdgcn_exp2f(ebuf[BI][k] * L2E);           \
    STEP(BI, 0, 0);                                                 \
    STEP(BI, 1, 1);                                                 \
    STEP(BI, 2, 0);                                                 \
    STEP(BI, 3, 1);                                                 \
    float m_ = __builtin_amdgcn_readfirstlane(av);                  \
    m_ = fmaxf(m_, 1e-30f);                                         \
    av *= __builtin_amdgcn_rcpf(m_);                                \
    LS += __builtin_amdgcn_logf(m_);  /* v_log_f32 = log2 */        \
  } while (0)

__global__ __launch_bounds__(64, 2) void crf_fwd(
    const float* __restrict__ emit, const float* __restrict__ trans,
    const int* __restrict__ tags, const int* __restrict__ lengths,
    float* __restrict__ out, int B)
{
  __shared__ float s_trans[TT * TT];
  {
    const float4* t4 = (const float4*)trans;
    float4* st = (float4*)s_trans;
#pragma unroll
    for (int k = 0; k < 4; ++k)
      st[threadIdx.x + 64 * k] = t4[threadIdx.x + 64 * k];
  }
  __syncthreads();

  const int lane = threadIdx.x & 63;
  const int j16  = lane & 15;
  const int bit4 = (lane >> 4) & 1;
  const int bit5 = (lane >> 5) & 1;
  const int b = blockIdx.x;

  // Q-layout: av[lane] = a[16*bit4 + j16]; step outputs columns jcolQ.
  // R-layout: av[lane] = a[16*bit5 + j16]; outputs jcolR.
  const int iQ    = 16 * bit4 + j16;
  const int jcolQ = 16 * bit5 + j16;
  const int jcolR = 16 * bit4 + j16;

  float EcQ[16], EcR[16];
#pragma unroll
  for (int i = 0; i < 16; ++i) {
    EcQ[i] = __builtin_amdgcn_exp2f(s_trans[(16 * bit4 + i) * TT + jcolQ] * L2E);
    EcR[i] = __builtin_amdgcn_exp2f(s_trans[(16 * bit5 + i) * TT + jcolR] * L2E);
  }

  const int len = lengths[b];
  const float* erow = emit + (size_t)b * (LL * TT);
  const int*  trow  = tags + (size_t)b * LL;

  // t = 0 prologue (layout Q)
  float e0   = erow[iQ];
  int   ptag = trow[0];
  float av   = __builtin_amdgcn_exp2f(e0 * L2E);
  float gacc = ((lane < 32) && (iQ == ptag)) ? e0 : 0.f;
  float LS   = 0.f;

  const int nch = (len - 1 + 3) >> 2;   // 4-step chunks
  const int nmi = (nch + 3) >> 2;       // macro-iters of 4 chunks (16 steps)

  // circular buffers: 4 chunks x (4 emit + 4 tags), statically indexed
  float ebuf[4][4];
  int   tbuf[4][4];

  LOADG(0, 0);
  LOADG(1, 1);
  LOADG(2, 2);

  int c0 = 0;
#pragma unroll 1
  for (int mi = 0; mi < nmi; ++mi, c0 += 4) {
    LOADG(3, c0 + 3);  PROC(0, c0);
    LOADG(0, c0 + 4);  PROC(1, c0 + 1);
    LOADG(1, c0 + 5);  PROC(2, c0 + 2);
    LOADG(2, c0 + 6);  PROC(3, c0 + 3);
  }

  // reductions over 64 lanes: alphas appear exactly twice -> S = 2*sum(a)
  float s  = av;
  float gs = gacc;
#pragma unroll
  for (int m = 1; m <= 32; m <<= 1) {
    s  += __shfl_xor(s, m);
    gs += __shfl_xor(gs, m);
  }
  float logz = (__builtin_amdgcn_logf(s) - 1.0f + LS) * LN2f;
  if (lane == 0) out[b] = logz - gs;
}

extern "C" void kernel_launch(void* const* d_in, const int* in_sizes, int n_in,
                              void* d_out, int out_size, void* d_ws, size_t ws_size,
                              hipStream_t stream) {
  const float* emit    = (const float*)d_in[0];
  const float* trans   = (const float*)d_in[1];
  const int*   tags    = (const int*)d_in[2];
  const int*   lengths = (const int*)d_in[3];
  float*       out     = (float*)d_out;
  const int B = in_sizes[3];             // lengths is (B,)
  hipLaunchKernelGGL(crf_fwd, dim3(B), dim3(64), 0, stream,
                     emit, trans, tags, lengths, out, B);
}